// Round 18
// baseline (135.916 us; speedup 1.0000x reference)
//
#include <hip/hip_runtime.h>
#include <cstdint>

#define NTOK 2048
#define DIM 512
#define EDIM 2048
#define BATCH 4
#define HEADS 8
#define BNROWS 8192   /* B*N */
#define INV_N (1.0f/2048.0f)

typedef unsigned short u16;
typedef __bf16 bf16x8 __attribute__((ext_vector_type(8)));
typedef u16   u16x8  __attribute__((ext_vector_type(8)));
typedef u16   u16x4  __attribute__((ext_vector_type(4)));
typedef float f32x4  __attribute__((ext_vector_type(4)));

__device__ __forceinline__ u16 f2bf(float f) {
  union { float f; uint32_t u; } v; v.f = f;
  uint32_t r = v.u + 0x7FFFu + ((v.u >> 16) & 1u);   // RNE
  return (u16)(r >> 16);
}
__device__ __forceinline__ u16 f2bfc(float f) {     // compiler cast (packs to cvt_pk, RNE)
  return __builtin_bit_cast(u16, (__bf16)f);
}
__device__ __forceinline__ float bf2f(u16 b) {
  union { uint32_t u; float f; } v; v.u = ((uint32_t)b) << 16;
  return v.f;
}
__device__ __forceinline__ bf16x8 ldb(const u16* p) {
  u16x8 r = *(const u16x8*)p;
  return __builtin_bit_cast(bf16x8, r);
}
#define MFMA16(a,b,c) __builtin_amdgcn_mfma_f32_16x16x32_bf16((a),(b),(c),0,0,0)

// silu with NR-refined reciprocal: rcp error squared (<2^-24) => numerically
// equivalent to exact division (round 6: RAW rcp is NOT acceptable). Clamp
// avoids inf -> NaN in the NR step.
__device__ __forceinline__ float silu_nr(float s) {
  float e = __expf(-s);
  e = fminf(e, 1.7e38f);
  float d = 1.0f + e;
  float r = __builtin_amdgcn_rcpf(d);
  r = r * fmaf(-d, r, 2.0f);
  return s * r;
}

// async global->LDS, 16B per lane; lds base must be wave-uniform
__device__ __forceinline__ void gload16(const u16* g, u16* lds) {
  __builtin_amdgcn_global_load_lds(
      (const __attribute__((address_space(1))) void*)g,
      (__attribute__((address_space(3))) void*)lds, 16, 0, 0);
}

// ---------------- fused prologue: uvqk transpose-cast | ow cast | ln1 ----------------
__global__ __launch_bounds__(256) void k_pre(const float* __restrict__ uvqk,
                                             const float* __restrict__ ow,
                                             const float* __restrict__ x,
                                             u16* __restrict__ uvqk_t,
                                             u16* __restrict__ ow_bf,
                                             u16* __restrict__ xn) {
  __shared__ float tile[32][33];
  int bid = blockIdx.x, tid = threadIdx.x;
  if (bid < 1024) {
    // uvqk: f32 [512][2048] -> bf16 [2048][512]
    int tx = tid & 31, ty = tid >> 5;
    int j0 = (bid & 63) * 32, k0 = (bid >> 6) * 32;
#pragma unroll
    for (int r = ty; r < 32; r += 8)
      tile[r][tx] = uvqk[(size_t)(k0 + r) * EDIM + j0 + tx];
    __syncthreads();
#pragma unroll
    for (int r = ty; r < 32; r += 8)
      uvqk_t[(size_t)(j0 + r) * DIM + k0 + tx] = f2bfc(tile[tx][r]);
  } else if (bid < 1280) {
    // ow cast: 512*512 f32 -> bf16
    int i4 = (bid - 1024) * 1024 + tid * 4;
    float4 v = *(const float4*)(ow + i4);
    u16x4 o = {f2bfc(v.x), f2bfc(v.y), f2bfc(v.z), f2bfc(v.w)};
    *(u16x4*)(ow_bf + i4) = o;
  } else {
    // ln1: 4 rows per block
    int lane = tid & 63, wid = tid >> 6;
    size_t row = (size_t)(bid - 1280) * 4 + wid;
    const float* xr = x + row * DIM;
    float4 a = ((const float4*)xr)[lane * 2];
    float4 b = ((const float4*)xr)[lane * 2 + 1];
    float s = a.x + a.y + a.z + a.w + b.x + b.y + b.z + b.w;
#pragma unroll
    for (int o = 32; o; o >>= 1) s += __shfl_xor(s, o);
    float mu = s * (1.0f / DIM);
    float d[8] = {a.x - mu, a.y - mu, a.z - mu, a.w - mu,
                  b.x - mu, b.y - mu, b.z - mu, b.w - mu};
    float v = 0.f;
#pragma unroll
    for (int j = 0; j < 8; ++j) v += d[j] * d[j];
#pragma unroll
    for (int o = 32; o; o >>= 1) v += __shfl_xor(v, o);
    float rs = rsqrtf(v * (1.0f / DIM) + 1e-6f);
    u16x8 o8;
#pragma unroll
    for (int j = 0; j < 8; ++j) o8[j] = f2bfc(d[j] * rs);
    *(u16x8*)(xn + row * DIM + lane * 8) = o8;
  }
}

// ---------------- GEMM1 v2: 128x256 tile, wave-tile 64x128 ----------------
__global__ __launch_bounds__(256, 2) void k_gemm1(const u16* __restrict__ A,
                                                  const u16* __restrict__ Bt,
                                                  u16* __restrict__ P,
                                                  u16* __restrict__ vt) {
  __shared__ u16 As[128 * 64];          // 16KB
  __shared__ u16 Bs[256 * 64];          // 32KB
  int tid = threadIdx.x, lane = tid & 63, wid = tid >> 6;
  int lm = lane & 15, lg = lane >> 4;
  int wr = wid >> 1, wc = wid & 1;      // 2x2 waves; wave tile 64 rows x 128 cols

  int bid = blockIdx.x;                 // 0..511
  int xcd = bid & 7, idx = bid >> 3;    // 64 work-items per XCD
  int r0 = (xcd * 8 + (idx >> 3)) * 128;   // 8 row-panels per XCD
  int c0 = (idx & 7) * 256;                // 8 col-blocks (N=2048)

  int srow = tid >> 3;                  // 0..31: staging row within 32-row slab
  int scol = ((lane & 7) ^ (lane >> 3)) * 8;  // pre-swizzled source col

  f32x4 acc[4][8];
  f32x4 z = {0.f, 0.f, 0.f, 0.f};
#pragma unroll
  for (int mt = 0; mt < 4; ++mt)
#pragma unroll
    for (int nt = 0; nt < 8; ++nt) acc[mt][nt] = z;

  int ksw = (lm & 7) << 3;              // fragment-read XOR for this lane

  for (int ks = 0; ks < DIM / 64; ++ks) {
#pragma unroll
    for (int it = 0; it < 4; ++it)
      gload16(A + (size_t)(r0 + it * 32 + srow) * DIM + ks * 64 + scol,
              As + it * 2048 + wid * 512);
#pragma unroll
    for (int it = 0; it < 8; ++it)
      gload16(Bt + (size_t)(c0 + it * 32 + srow) * DIM + ks * 64 + scol,
              Bs + it * 2048 + wid * 512);
    __syncthreads();

#pragma unroll
    for (int kk = 0; kk < 2; ++kk) {
      bf16x8 am[4], bn[8];
#pragma unroll
      for (int mt = 0; mt < 4; ++mt)
        am[mt] = ldb(&As[(wr * 64 + mt * 16 + lm) * 64 + ((kk * 32 + lg * 8) ^ ksw)]);
#pragma unroll
      for (int nt = 0; nt < 8; ++nt)
        bn[nt] = ldb(&Bs[(wc * 128 + nt * 16 + lm) * 64 + ((kk * 32 + lg * 8) ^ ksw)]);
#pragma unroll
      for (int mt = 0; mt < 4; ++mt)
#pragma unroll
        for (int nt = 0; nt < 8; ++nt)
          acc[mt][nt] = MFMA16(am[mt], bn[nt], acc[mt][nt]);
    }
    __syncthreads();
  }

  bool isv = (c0 >= 512) && (c0 < 1024);   // this block's 256 cols all in v-slice?
  int btc = r0 >> 11;                   // batch index
  int nbw = (r0 & 2047) + wr * 64;      // n base for this wave
  int cw = c0 + wc * 128;               // wave's first col

#pragma unroll
  for (int mt = 0; mt < 4; ++mt)
#pragma unroll
    for (int nt = 0; nt < 8; ++nt) {
      u16 pv[4];
#pragma unroll
      for (int i = 0; i < 4; ++i)
        pv[i] = f2bfc(silu_nr(acc[mt][nt][i]));
      if (isv) {
        int hv = (cw + nt * 16 - 512) >> 6;
        int e = (nt & 3) * 16 + lm;
        int n = nbw + mt * 16 + lg * 4;
        u16x4 pk = {pv[0], pv[1], pv[2], pv[3]};
        *(u16x4*)(vt + ((size_t)(btc * 8 + hv) * 64 + e) * NTOK + n) = pk;
      } else {
        int col = cw + nt * 16 + lm;
#pragma unroll
        for (int i = 0; i < 4; ++i) {
          size_t row = r0 + wr * 64 + mt * 16 + lg * 4 + i;
          P[row * EDIM + col] = pv[i];
        }
      }
    }
}

// ---------------- HSTU attention v7: V fragments direct from L2 ----------------
// attn was CU-LDS-read-BW-bound (~1400 of ~1540 cy/step were ds_read).  V^T
// (vt) is fragment-friendly in global and L2-resident (1MB/XCD) -> read vf
// straight from L2, issued early and hidden under QK^T+silu.  Removes 8 of 18
// LDS reads/wave-step + half the staging; K stays staged (4KB-stride source).
// LDS 40->24KB; 1024 blocks, 4/CU; boustrophedon map (per-CU sum 66 steps).
// DO NOT trade occupancy for LDS traffic (round 12: 48KB => 89us).
__global__ __launch_bounds__(256) void k_attn(const u16* __restrict__ proj,
                                              const u16* __restrict__ vt,
                                              u16* __restrict__ attnb) {
  __shared__ u16 k0buf[4096];               // K[64][64]  8KB
  __shared__ u16 k1buf[4096];               // 8KB
  __shared__ u16 p_lds[4][16][64];          // per-wave P[q 16][m 64], XOR-swizzled, 8KB
  int tid = threadIdx.x, lane = tid & 63, w = tid >> 6;
  int lm = lane & 15, lg = lane >> 4;

  int bid = blockIdx.x;                     // 0..1023
  int xcd = bid & 7, idx = bid >> 3;        // idx 0..127
  int j = idx >> 2, pj = j & 7;             // j 0..31
  // boustrophedon rounds: {31-p, 16+p, 15-p, p} -> per-CU sum constant
  int qtile = (j < 8) ? (31 - pj) : (j < 16) ? (16 + pj)
                      : (j < 24) ? (15 - pj) : pj;
  int bh = (xcd << 2) + (idx & 3);          // 4 heads per XCD (L2 locality)
  int b = bh >> 3, h = bh & 7;
  int n0 = qtile * 64;
  int nrow = n0 + w * 16;                   // wave's first q row
  int nlm = nrow + lm;                      // this lane's q (column of S^T)

  const u16* pb = proj + (size_t)b * NTOK * EDIM;
  const u16* kb = pb + 1536 + h * 64;
  const u16* vb = vt + (size_t)bh * 64 * NTOK;

  f32x4 z = {0.f, 0.f, 0.f, 0.f};

  int sr = lane >> 3;
  int sc = ((lane & 7) ^ sr) * 8;           // u16 units (pre-swizzled source)
  const u16* ks0 = kb + (size_t)(w * 16 + sr) * EDIM + sc;
  const u16* ks1 = kb + (size_t)(w * 16 + 8 + sr) * EDIM + sc;
  // per-lane V fragment base: vf[kk][et] = vfb + (et*16)*NTOK + m0 + kk*32
  const u16* vfb = vb + (size_t)lm * NTOK + lg * 8;

  const u16* qrow = pb + (size_t)nlm * EDIM + 1024 + h * 64 + lg * 8;
  bf16x8 qf0 = ldb(qrow), qf1 = ldb(qrow + 32);

  f32x4 acc[4];
#pragma unroll
  for (int et = 0; et < 4; ++et) acc[et] = z;

  int psw = (lm & 7) << 3;                  // p_lds XOR swizzle for this lane

  gload16(ks0, k0buf + (w * 16) * 64);
  gload16(ks1, k0buf + (w * 16 + 8) * 64);
  asm volatile("s_waitcnt vmcnt(0)" ::: "memory");
  __builtin_amdgcn_s_barrier();

  int ntl = qtile + 1;
  for (int t = 0; t < ntl; ++t) {
    const u16* kt = (t & 1) ? k1buf : k0buf;
    int m0 = t * 64;
    if (t + 1 < ntl) {                      // prefetch next K tile
      u16* kd = ((t + 1) & 1) ? k1buf : k0buf;
      size_t ko = (size_t)(t + 1) * 64 * EDIM;
      gload16(ks0 + ko, kd + (w * 16) * 64);
      gload16(ks1 + ko, kd + (w * 16 + 8) * 64);
    }
    // ---- issue V fragment loads early (L2-resident); hidden under QK^T
    bf16x8 vf[2][4];
#pragma unroll
    for (int kk = 0; kk < 2; ++kk)
#pragma unroll
      for (int et = 0; et < 4; ++et)
        vf[kk][et] = ldb(vfb + (size_t)(et * 16) * NTOK + m0 + kk * 32);
    // ---- QK^T swapped: S^T[m][q]; K fragments from LDS (swizzled)
    bf16x8 kf[4][2];
#pragma unroll
    for (int mb = 0; mb < 4; ++mb)
#pragma unroll
      for (int kk = 0; kk < 2; ++kk)
        kf[mb][kk] = ldb(&kt[(mb * 16 + lm) * 64 +
                             ((kk * 32 + lg * 8) ^ ((lm & 7) << 3))]);
    if (t == qtile) {                       // diagonal tile: masked
#pragma unroll
      for (int mb = 0; mb < 4; ++mb) {
        f32x4 s = MFMA16(kf[mb][0], qf0, z);
        s = MFMA16(kf[mb][1], qf1, s);
        int m = m0 + mb * 16 + lg * 4;
        u16x4 pk;
#pragma unroll
        for (int i = 0; i < 4; ++i)
          pk[i] = (m + i <= nlm) ? f2bfc(silu_nr(s[i])) : (u16)0;
        *(u16x4*)&p_lds[w][lm][(mb * 16 + lg * 4) ^ psw] = pk;
      }
    } else {                                // full tile
#pragma unroll
      for (int mb = 0; mb < 4; ++mb) {
        f32x4 s = MFMA16(kf[mb][0], qf0, z);
        s = MFMA16(kf[mb][1], qf1, s);
        u16x4 pk;
#pragma unroll
        for (int i = 0; i < 4; ++i) pk[i] = f2bfc(silu_nr(s[i]));
        *(u16x4*)&p_lds[w][lm][(mb * 16 + lg * 4) ^ psw] = pk;
      }
    }
    // ---- PV
    bf16x8 pf0 = ldb(&p_lds[w][lm][(lg * 8) ^ psw]);
    bf16x8 pf1 = ldb(&p_lds[w][lm][(32 + lg * 8) ^ psw]);
#pragma unroll
    for (int et = 0; et < 4; ++et) {
      acc[et] = MFMA16(pf0, vf[0][et], acc[et]);
      acc[et] = MFMA16(pf1, vf[1][et], acc[et]);
    }
    asm volatile("s_waitcnt vmcnt(0)" ::: "memory");
    __builtin_amdgcn_s_barrier();
  }

#pragma unroll
  for (int et = 0; et < 4; ++et)
#pragma unroll
    for (int i = 0; i < 4; ++i)
      attnb[((size_t)b * NTOK + nrow + lg * 4 + i) * DIM +
            h * 64 + et * 16 + lm] = f2bfc(acc[et][i] * INV_N);
}

// ---------------- fused LN2 + GEMM2 (256 x 32 rows; attn bf16) ----------------
__global__ __launch_bounds__(256) void k_gemm2f(const u16* __restrict__ attnb,
                                                const u16* __restrict__ proj,
                                                const u16* __restrict__ Bw,
                                                const float* __restrict__ o_b,
                                                const float* __restrict__ x,
                                                float* __restrict__ out) {
  __shared__ u16 os[32 * 512];              // LN(attn)*u, bf16, swizzled cols
  int tid = threadIdx.x, lane = tid & 63, w = tid >> 6;
  int lm = lane & 15, lg = lane >> 4;

  int bid = blockIdx.x;                     // 0..255
  int xcd = bid & 7, idx = bid >> 3;        // 32 blocks per XCD
  int r0 = (xcd * 32 + idx) * 32;           // 1024-row panel per XCD

  // ---- Phase 1: LN rows w*8 .. w*8+7 ----
#pragma unroll
  for (int rr = 0; rr < 8; ++rr) {
    int r = w * 8 + rr;
    u16x8 a8 = *(const u16x8*)(attnb + (size_t)(r0 + r) * DIM + lane * 8);
    float av[8];
#pragma unroll
    for (int j = 0; j < 8; ++j) av[j] = bf2f(a8[j]);
    float s = av[0] + av[1] + av[2] + av[3] + av[4] + av[5] + av[6] + av[7];
#pragma unroll
    for (int o = 32; o; o >>= 1) s += __shfl_xor(s, o);
    float mu = s * (1.0f / DIM);
    float d[8];
#pragma unroll
    for (int j = 0; j < 8; ++j) d[j] = av[j] - mu;
    float v = 0.f;
#pragma unroll
    for (int j = 0; j < 8; ++j) v += d[j] * d[j];
#pragma unroll
    for (int o = 32; o; o >>= 1) v += __shfl_xor(v, o);
    float rs = rsqrtf(v * (1.0f / DIM) + 1e-6f);
    u16x8 u8 = *(const u16x8*)(proj + (size_t)(r0 + r) * EDIM + lane * 8);
    u16x8 o8;
#pragma unroll
    for (int j = 0; j < 8; ++j) o8[j] = f2bfc(bf2f(u8[j]) * (d[j] * rs));
    *(u16x8*)&os[r * 512 + ((lane * 8) ^ ((r & 7) << 3))] = o8;
  }
  __syncthreads();

  // ---- Phase 2: GEMM, wave w covers cols w*128..w*128+127 ----
  int cb = w * 128;
  f32x4 acc[2][8];
  f32x4 z = {0.f, 0.f, 0.f, 0.f};
#pragma unroll
  for (int mt = 0; mt < 2; ++mt)
#pragma unroll
    for (int nt = 0; nt < 8; ++nt) acc[mt][nt] = z;

#pragma unroll 2
  for (int kc = 0; kc < 16; ++kc) {
    bf16x8 af[2];
#pragma unroll
    for (int mt = 0; mt < 2; ++mt)
      af[mt] = ldb(&os[(mt * 16 + lm) * 512 +
                       ((kc * 32 + lg * 8) ^ ((lm & 7) << 3))]);
    bf16x8 bfr[8];
#pragma unroll
    for (int nt = 0; nt < 8; ++nt)
      bfr[nt] = ldb(Bw + (size_t)(cb + nt * 16 + lm) * DIM + kc * 32 + lg * 8);
#pragma unroll
    for (int mt = 0; mt < 2; ++mt)
#pragma unroll
      for (int nt = 0; nt < 8; ++nt)
        acc[mt][nt] = MFMA16(af[mt], bfr[nt], acc[mt][nt]);
  }

#pragma unroll
  for (int mt = 0; mt < 2; ++mt)
#pragma unroll
    for (int nt = 0; nt < 8; ++nt)
#pragma unroll
      for (int i = 0; i < 4; ++i) {
        size_t row = r0 + mt * 16 + lg * 4 + i;
        int col = cb + nt * 16 + lm;
        out[row * DIM + col] = acc[mt][nt][i] + o_b[col] + x[row * DIM + col];
      }
}

extern "C" void kernel_launch(void* const* d_in, const int* in_sizes, int n_in,
                              void* d_out, int out_size, void* d_ws, size_t ws_size,
                              hipStream_t stream) {
  const float* x    = (const float*)d_in[0];
  // d_in[1] = invalid_attn_mask: structurally causal tril; applied as predicate.
  const float* uvqk = (const float*)d_in[2];
  const float* o_w  = (const float*)d_in[3];
  const float* o_b  = (const float*)d_in[4];
  float* out = (float*)d_out;

  u16* uvqk_t = (u16*)d_ws;                         // [2048][512] bf16   2MB
  u16* ow_bf  = uvqk_t + (size_t)EDIM * DIM;        // [512][512]  bf16   0.5MB
  u16* xn     = ow_bf + (size_t)DIM * DIM;          // [8192][512] bf16   8MB
  u16* proj   = xn + (size_t)BNROWS * DIM;          // [8192][2048] bf16  32MB
  u16* attnb  = proj + (size_t)BNROWS * EDIM;       // [8192][512] bf16   8MB
  u16* vt     = attnb + (size_t)BNROWS * DIM;       // [32][64][2048] bf16 8MB

  k_pre<<<dim3(3328), 256, 0, stream>>>(uvqk, o_w, x, uvqk_t, ow_bf, xn);
  k_gemm1<<<dim3(512), 256, 0, stream>>>(xn, uvqk_t, proj, vt);
  k_attn<<<dim3(1024), 256, 0, stream>>>(proj, vt, attnb);
  k_gemm2f<<<dim3(256), 256, 0, stream>>>(attnb, proj, ow_bf, o_b, x, out);
}

// Round 19
// 97.254 us; speedup vs baseline: 1.3975x; 1.3975x over previous
//
#include <hip/hip_runtime.h>
#include <cstdint>

#define NTOK 2048
#define DIM 512
#define EDIM 2048
#define BATCH 4
#define HEADS 8
#define BNROWS 8192   /* B*N */
#define INV_N (1.0f/2048.0f)

typedef unsigned short u16;
typedef __bf16 bf16x8 __attribute__((ext_vector_type(8)));
typedef u16   u16x8  __attribute__((ext_vector_type(8)));
typedef u16   u16x4  __attribute__((ext_vector_type(4)));
typedef float f32x4  __attribute__((ext_vector_type(4)));

__device__ __forceinline__ u16 f2bf(float f) {
  union { float f; uint32_t u; } v; v.f = f;
  uint32_t r = v.u + 0x7FFFu + ((v.u >> 16) & 1u);   // RNE
  return (u16)(r >> 16);
}
__device__ __forceinline__ u16 f2bfc(float f) {     // compiler cast (packs to cvt_pk, RNE)
  return __builtin_bit_cast(u16, (__bf16)f);
}
__device__ __forceinline__ float bf2f(u16 b) {
  union { uint32_t u; float f; } v; v.u = ((uint32_t)b) << 16;
  return v.f;
}
__device__ __forceinline__ bf16x8 ldb(const u16* p) {
  u16x8 r = *(const u16x8*)p;
  return __builtin_bit_cast(bf16x8, r);
}
#define MFMA16(a,b,c) __builtin_amdgcn_mfma_f32_16x16x32_bf16((a),(b),(c),0,0,0)

// silu with NR-refined reciprocal: rcp error squared (<2^-24) => numerically
// equivalent to exact division (round 6: RAW rcp is NOT acceptable). Clamp
// avoids inf -> NaN in the NR step.
__device__ __forceinline__ float silu_nr(float s) {
  float e = __expf(-s);
  e = fminf(e, 1.7e38f);
  float d = 1.0f + e;
  float r = __builtin_amdgcn_rcpf(d);
  r = r * fmaf(-d, r, 2.0f);
  return s * r;
}

// async global->LDS, 16B per lane; lds base must be wave-uniform
__device__ __forceinline__ void gload16(const u16* g, u16* lds) {
  __builtin_amdgcn_global_load_lds(
      (const __attribute__((address_space(1))) void*)g,
      (__attribute__((address_space(3))) void*)lds, 16, 0, 0);
}

// ---------------- fused prologue: uvqk transpose-cast | ow cast | ln1 ----------------
__global__ __launch_bounds__(256) void k_pre(const float* __restrict__ uvqk,
                                             const float* __restrict__ ow,
                                             const float* __restrict__ x,
                                             u16* __restrict__ uvqk_t,
                                             u16* __restrict__ ow_bf,
                                             u16* __restrict__ xn) {
  __shared__ float tile[32][33];
  int bid = blockIdx.x, tid = threadIdx.x;
  if (bid < 1024) {
    // uvqk: f32 [512][2048] -> bf16 [2048][512]
    int tx = tid & 31, ty = tid >> 5;
    int j0 = (bid & 63) * 32, k0 = (bid >> 6) * 32;
#pragma unroll
    for (int r = ty; r < 32; r += 8)
      tile[r][tx] = uvqk[(size_t)(k0 + r) * EDIM + j0 + tx];
    __syncthreads();
#pragma unroll
    for (int r = ty; r < 32; r += 8)
      uvqk_t[(size_t)(j0 + r) * DIM + k0 + tx] = f2bfc(tile[tx][r]);
  } else if (bid < 1280) {
    // ow cast: 512*512 f32 -> bf16
    int i4 = (bid - 1024) * 1024 + tid * 4;
    float4 v = *(const float4*)(ow + i4);
    u16x4 o = {f2bfc(v.x), f2bfc(v.y), f2bfc(v.z), f2bfc(v.w)};
    *(u16x4*)(ow_bf + i4) = o;
  } else {
    // ln1: 4 rows per block
    int lane = tid & 63, wid = tid >> 6;
    size_t row = (size_t)(bid - 1280) * 4 + wid;
    const float* xr = x + row * DIM;
    float4 a = ((const float4*)xr)[lane * 2];
    float4 b = ((const float4*)xr)[lane * 2 + 1];
    float s = a.x + a.y + a.z + a.w + b.x + b.y + b.z + b.w;
#pragma unroll
    for (int o = 32; o; o >>= 1) s += __shfl_xor(s, o);
    float mu = s * (1.0f / DIM);
    float d[8] = {a.x - mu, a.y - mu, a.z - mu, a.w - mu,
                  b.x - mu, b.y - mu, b.z - mu, b.w - mu};
    float v = 0.f;
#pragma unroll
    for (int j = 0; j < 8; ++j) v += d[j] * d[j];
#pragma unroll
    for (int o = 32; o; o >>= 1) v += __shfl_xor(v, o);
    float rs = rsqrtf(v * (1.0f / DIM) + 1e-6f);
    u16x8 o8;
#pragma unroll
    for (int j = 0; j < 8; ++j) o8[j] = f2bfc(d[j] * rs);
    *(u16x8*)(xn + row * DIM + lane * 8) = o8;
  }
}

// ---------------- GEMM1 v2: 128x256 tile, wave-tile 64x128 ----------------
__global__ __launch_bounds__(256, 2) void k_gemm1(const u16* __restrict__ A,
                                                  const u16* __restrict__ Bt,
                                                  u16* __restrict__ P,
                                                  u16* __restrict__ vt) {
  __shared__ u16 As[128 * 64];          // 16KB
  __shared__ u16 Bs[256 * 64];          // 32KB
  int tid = threadIdx.x, lane = tid & 63, wid = tid >> 6;
  int lm = lane & 15, lg = lane >> 4;
  int wr = wid >> 1, wc = wid & 1;      // 2x2 waves; wave tile 64 rows x 128 cols

  int bid = blockIdx.x;                 // 0..511
  int xcd = bid & 7, idx = bid >> 3;    // 64 work-items per XCD
  int r0 = (xcd * 8 + (idx >> 3)) * 128;   // 8 row-panels per XCD
  int c0 = (idx & 7) * 256;                // 8 col-blocks (N=2048)

  int srow = tid >> 3;                  // 0..31: staging row within 32-row slab
  int scol = ((lane & 7) ^ (lane >> 3)) * 8;  // pre-swizzled source col

  f32x4 acc[4][8];
  f32x4 z = {0.f, 0.f, 0.f, 0.f};
#pragma unroll
  for (int mt = 0; mt < 4; ++mt)
#pragma unroll
    for (int nt = 0; nt < 8; ++nt) acc[mt][nt] = z;

  int ksw = (lm & 7) << 3;              // fragment-read XOR for this lane

  for (int ks = 0; ks < DIM / 64; ++ks) {
#pragma unroll
    for (int it = 0; it < 4; ++it)
      gload16(A + (size_t)(r0 + it * 32 + srow) * DIM + ks * 64 + scol,
              As + it * 2048 + wid * 512);
#pragma unroll
    for (int it = 0; it < 8; ++it)
      gload16(Bt + (size_t)(c0 + it * 32 + srow) * DIM + ks * 64 + scol,
              Bs + it * 2048 + wid * 512);
    __syncthreads();

#pragma unroll
    for (int kk = 0; kk < 2; ++kk) {
      bf16x8 am[4], bn[8];
#pragma unroll
      for (int mt = 0; mt < 4; ++mt)
        am[mt] = ldb(&As[(wr * 64 + mt * 16 + lm) * 64 + ((kk * 32 + lg * 8) ^ ksw)]);
#pragma unroll
      for (int nt = 0; nt < 8; ++nt)
        bn[nt] = ldb(&Bs[(wc * 128 + nt * 16 + lm) * 64 + ((kk * 32 + lg * 8) ^ ksw)]);
#pragma unroll
      for (int mt = 0; mt < 4; ++mt)
#pragma unroll
        for (int nt = 0; nt < 8; ++nt)
          acc[mt][nt] = MFMA16(am[mt], bn[nt], acc[mt][nt]);
    }
    __syncthreads();
  }

  bool isv = (c0 >= 512) && (c0 < 1024);   // this block's 256 cols all in v-slice?
  int btc = r0 >> 11;                   // batch index
  int nbw = (r0 & 2047) + wr * 64;      // n base for this wave
  int cw = c0 + wc * 128;               // wave's first col

#pragma unroll
  for (int mt = 0; mt < 4; ++mt)
#pragma unroll
    for (int nt = 0; nt < 8; ++nt) {
      u16 pv[4];
#pragma unroll
      for (int i = 0; i < 4; ++i)
        pv[i] = f2bfc(silu_nr(acc[mt][nt][i]));
      if (isv) {
        int hv = (cw + nt * 16 - 512) >> 6;
        int e = (nt & 3) * 16 + lm;
        int n = nbw + mt * 16 + lg * 4;
        u16x4 pk = {pv[0], pv[1], pv[2], pv[3]};
        *(u16x4*)(vt + ((size_t)(btc * 8 + hv) * 64 + e) * NTOK + n) = pk;
      } else {
        int col = cw + nt * 16 + lm;
#pragma unroll
        for (int i = 0; i < 4; ++i) {
          size_t row = r0 + wr * 64 + mt * 16 + lg * 4 + i;
          P[row * EDIM + col] = pv[i];
        }
      }
    }
}

// ---------------- HSTU attention v6b + bf16 out (round-17 proven, 42.3us) ----------------
// 1024 blocks = exactly 4/CU resident; boustrophedon j->qtile map makes every
// CU's four blocks sum to exactly 66 m-steps.  LDS-staged K AND V: every wave
// reads the full K/V tile, so staging amortizes the 4x cross-wave redundancy
// (round 18: V direct from L2 => 4x L2 traffic => 83us.  round 12: 48KB LDS
// => occupancy cliff => 89us.  This 40KB/4-block config is the optimum.)
__global__ __launch_bounds__(256) void k_attn(const u16* __restrict__ proj,
                                              const u16* __restrict__ vt,
                                              u16* __restrict__ attnb) {
  __shared__ u16 kv0[8192];                 // K[64][64] | V^T[64][64]  16KB
  __shared__ u16 kv1[8192];                 // 16KB
  __shared__ u16 p_lds[4][16][64];          // per-wave P[q 16][m 64], XOR-swizzled, 8KB
  int tid = threadIdx.x, lane = tid & 63, w = tid >> 6;
  int lm = lane & 15, lg = lane >> 4;

  int bid = blockIdx.x;                     // 0..1023
  int xcd = bid & 7, idx = bid >> 3;        // idx 0..127
  int j = idx >> 2, pj = j & 7;             // j 0..31
  // boustrophedon rounds: {31-p, 16+p, 15-p, p} -> per-CU sum constant
  int qtile = (j < 8) ? (31 - pj) : (j < 16) ? (16 + pj)
                      : (j < 24) ? (15 - pj) : pj;
  int bh = (xcd << 2) + (idx & 3);          // 4 heads per XCD (L2 locality)
  int b = bh >> 3, h = bh & 7;
  int n0 = qtile * 64;
  int nrow = n0 + w * 16;                   // wave's first q row
  int nlm = nrow + lm;                      // this lane's q (column of S^T)

  const u16* pb = proj + (size_t)b * NTOK * EDIM;
  const u16* kb = pb + 1536 + h * 64;
  const u16* vb = vt + (size_t)bh * 64 * NTOK;

  f32x4 z = {0.f, 0.f, 0.f, 0.f};

  int sr = lane >> 3;
  int sc = ((lane & 7) ^ sr) * 8;           // u16 units (pre-swizzled source)
  const u16* ks0 = kb + (size_t)(w * 16 + sr) * EDIM + sc;
  const u16* ks1 = kb + (size_t)(w * 16 + 8 + sr) * EDIM + sc;
  const u16* vs0 = vb + (size_t)(w * 16 + sr) * NTOK + sc;
  const u16* vs1 = vb + (size_t)(w * 16 + 8 + sr) * NTOK + sc;

  const u16* qrow = pb + (size_t)nlm * EDIM + 1024 + h * 64 + lg * 8;
  bf16x8 qf0 = ldb(qrow), qf1 = ldb(qrow + 32);

  f32x4 acc[4];
#pragma unroll
  for (int et = 0; et < 4; ++et) acc[et] = z;

  int psw = (lm & 7) << 3;                  // p_lds XOR swizzle for this lane

  gload16(ks0, kv0 + (w * 16) * 64);
  gload16(ks1, kv0 + (w * 16 + 8) * 64);
  gload16(vs0, kv0 + 4096 + (w * 16) * 64);
  gload16(vs1, kv0 + 4096 + (w * 16 + 8) * 64);
  asm volatile("s_waitcnt vmcnt(0)" ::: "memory");
  __builtin_amdgcn_s_barrier();

  int ntl = qtile + 1;
  for (int t = 0; t < ntl; ++t) {
    const u16* kt = (t & 1) ? kv1 : kv0;
    const u16* vl = kt + 4096;
    if (t + 1 < ntl) {                      // prefetch next tile
      u16* kd = ((t + 1) & 1) ? kv1 : kv0;
      size_t ko = (size_t)(t + 1) * 64 * EDIM;
      size_t vo = (size_t)(t + 1) * 64;
      gload16(ks0 + ko, kd + (w * 16) * 64);
      gload16(ks1 + ko, kd + (w * 16 + 8) * 64);
      gload16(vs0 + vo, kd + 4096 + (w * 16) * 64);
      gload16(vs1 + vo, kd + 4096 + (w * 16 + 8) * 64);
    }
    bf16x8 kf[4][2];
#pragma unroll
    for (int mb = 0; mb < 4; ++mb)
#pragma unroll
      for (int kk = 0; kk < 2; ++kk)
        kf[mb][kk] = ldb(&kt[(mb * 16 + lm) * 64 +
                             ((kk * 32 + lg * 8) ^ ((lm & 7) << 3))]);
    if (t == qtile) {                       // diagonal tile: masked
#pragma unroll
      for (int mb = 0; mb < 4; ++mb) {
        f32x4 s = MFMA16(kf[mb][0], qf0, z);
        s = MFMA16(kf[mb][1], qf1, s);
        int m = t * 64 + mb * 16 + lg * 4;
        u16x4 pk;
#pragma unroll
        for (int i = 0; i < 4; ++i)
          pk[i] = (m + i <= nlm) ? f2bfc(silu_nr(s[i])) : (u16)0;
        *(u16x4*)&p_lds[w][lm][(mb * 16 + lg * 4) ^ psw] = pk;
      }
    } else {                                // full tile
#pragma unroll
      for (int mb = 0; mb < 4; ++mb) {
        f32x4 s = MFMA16(kf[mb][0], qf0, z);
        s = MFMA16(kf[mb][1], qf1, s);
        u16x4 pk;
#pragma unroll
        for (int i = 0; i < 4; ++i) pk[i] = f2bfc(silu_nr(s[i]));
        *(u16x4*)&p_lds[w][lm][(mb * 16 + lg * 4) ^ psw] = pk;
      }
    }
    bf16x8 vf[2][4];
#pragma unroll
    for (int kk = 0; kk < 2; ++kk)
#pragma unroll
      for (int et = 0; et < 4; ++et)
        vf[kk][et] = ldb(&vl[(et * 16 + lm) * 64 +
                             ((kk * 32 + lg * 8) ^ ((lm & 7) << 3))]);
    bf16x8 pf0 = ldb(&p_lds[w][lm][(lg * 8) ^ psw]);
    bf16x8 pf1 = ldb(&p_lds[w][lm][(32 + lg * 8) ^ psw]);
#pragma unroll
    for (int et = 0; et < 4; ++et) {
      acc[et] = MFMA16(pf0, vf[0][et], acc[et]);
      acc[et] = MFMA16(pf1, vf[1][et], acc[et]);
    }
    asm volatile("s_waitcnt vmcnt(0)" ::: "memory");
    __builtin_amdgcn_s_barrier();
  }

#pragma unroll
  for (int et = 0; et < 4; ++et)
#pragma unroll
    for (int i = 0; i < 4; ++i)
      attnb[((size_t)b * NTOK + nrow + lg * 4 + i) * DIM +
            h * 64 + et * 16 + lm] = f2bfc(acc[et][i] * INV_N);
}

// ---------------- fused LN2 + GEMM2 (256 x 32 rows; attn bf16) ----------------
__global__ __launch_bounds__(256) void k_gemm2f(const u16* __restrict__ attnb,
                                                const u16* __restrict__ proj,
                                                const u16* __restrict__ Bw,
                                                const float* __restrict__ o_b,
                                                const float* __restrict__ x,
                                                float* __restrict__ out) {
  __shared__ u16 os[32 * 512];              // LN(attn)*u, bf16, swizzled cols
  int tid = threadIdx.x, lane = tid & 63, w = tid >> 6;
  int lm = lane & 15, lg = lane >> 4;

  int bid = blockIdx.x;                     // 0..255
  int xcd = bid & 7, idx = bid >> 3;        // 32 blocks per XCD
  int r0 = (xcd * 32 + idx) * 32;           // 1024-row panel per XCD

  // ---- Phase 1: LN rows w*8 .. w*8+7 ----
#pragma unroll
  for (int rr = 0; rr < 8; ++rr) {
    int r = w * 8 + rr;
    u16x8 a8 = *(const u16x8*)(attnb + (size_t)(r0 + r) * DIM + lane * 8);
    float av[8];
#pragma unroll
    for (int j = 0; j < 8; ++j) av[j] = bf2f(a8[j]);
    float s = av[0] + av[1] + av[2] + av[3] + av[4] + av[5] + av[6] + av[7];
#pragma unroll
    for (int o = 32; o; o >>= 1) s += __shfl_xor(s, o);
    float mu = s * (1.0f / DIM);
    float d[8];
#pragma unroll
    for (int j = 0; j < 8; ++j) d[j] = av[j] - mu;
    float v = 0.f;
#pragma unroll
    for (int j = 0; j < 8; ++j) v += d[j] * d[j];
#pragma unroll
    for (int o = 32; o; o >>= 1) v += __shfl_xor(v, o);
    float rs = rsqrtf(v * (1.0f / DIM) + 1e-6f);
    u16x8 u8 = *(const u16x8*)(proj + (size_t)(r0 + r) * EDIM + lane * 8);
    u16x8 o8;
#pragma unroll
    for (int j = 0; j < 8; ++j) o8[j] = f2bfc(bf2f(u8[j]) * (d[j] * rs));
    *(u16x8*)&os[r * 512 + ((lane * 8) ^ ((r & 7) << 3))] = o8;
  }
  __syncthreads();

  // ---- Phase 2: GEMM, wave w covers cols w*128..w*128+127 ----
  int cb = w * 128;
  f32x4 acc[2][8];
  f32x4 z = {0.f, 0.f, 0.f, 0.f};
#pragma unroll
  for (int mt = 0; mt < 2; ++mt)
#pragma unroll
    for (int nt = 0; nt < 8; ++nt) acc[mt][nt] = z;

#pragma unroll 2
  for (int kc = 0; kc < 16; ++kc) {
    bf16x8 af[2];
#pragma unroll
    for (int mt = 0; mt < 2; ++mt)
      af[mt] = ldb(&os[(mt * 16 + lm) * 512 +
                       ((kc * 32 + lg * 8) ^ ((lm & 7) << 3))]);
    bf16x8 bfr[8];
#pragma unroll
    for (int nt = 0; nt < 8; ++nt)
      bfr[nt] = ldb(Bw + (size_t)(cb + nt * 16 + lm) * DIM + kc * 32 + lg * 8);
#pragma unroll
    for (int mt = 0; mt < 2; ++mt)
#pragma unroll
      for (int nt = 0; nt < 8; ++nt)
        acc[mt][nt] = MFMA16(af[mt], bfr[nt], acc[mt][nt]);
  }

#pragma unroll
  for (int mt = 0; mt < 2; ++mt)
#pragma unroll
    for (int nt = 0; nt < 8; ++nt)
#pragma unroll
      for (int i = 0; i < 4; ++i) {
        size_t row = r0 + mt * 16 + lg * 4 + i;
        int col = cb + nt * 16 + lm;
        out[row * DIM + col] = acc[mt][nt][i] + o_b[col] + x[row * DIM + col];
      }
}

extern "C" void kernel_launch(void* const* d_in, const int* in_sizes, int n_in,
                              void* d_out, int out_size, void* d_ws, size_t ws_size,
                              hipStream_t stream) {
  const float* x    = (const float*)d_in[0];
  // d_in[1] = invalid_attn_mask: structurally causal tril; applied as predicate.
  const float* uvqk = (const float*)d_in[2];
  const float* o_w  = (const float*)d_in[3];
  const float* o_b  = (const float*)d_in[4];
  float* out = (float*)d_out;

  u16* uvqk_t = (u16*)d_ws;                         // [2048][512] bf16   2MB
  u16* ow_bf  = uvqk_t + (size_t)EDIM * DIM;        // [512][512]  bf16   0.5MB
  u16* xn     = ow_bf + (size_t)DIM * DIM;          // [8192][512] bf16   8MB
  u16* proj   = xn + (size_t)BNROWS * DIM;          // [8192][2048] bf16  32MB
  u16* attnb  = proj + (size_t)BNROWS * EDIM;       // [8192][512] bf16   8MB
  u16* vt     = attnb + (size_t)BNROWS * DIM;       // [32][64][2048] bf16 8MB

  k_pre<<<dim3(3328), 256, 0, stream>>>(uvqk, o_w, x, uvqk_t, ow_bf, xn);
  k_gemm1<<<dim3(512), 256, 0, stream>>>(xn, uvqk_t, proj, vt);
  k_attn<<<dim3(1024), 256, 0, stream>>>(proj, vt, attnb);
  k_gemm2f<<<dim3(256), 256, 0, stream>>>(attnb, proj, ow_bf, o_b, x, out);
}